// Round 2
// baseline (9658.767 us; speedup 1.0000x reference)
//
#include <hip/hip_runtime.h>

// Fused 3-layer dilated LSTM (rates 1/2/4), T=512, B=128, D=H=256.
// One persistent 448-block kernel, wavefront-pipelined across layers:
//   blocks [0,64)   : layer 0 (rate 1, td 512, G_b=4)
//   blocks [64,192) : layer 1 (rate 2, td 256, G_b=8)
//   blocks [192,448): layer 2 (rate 4, td 128, G_b=16)
// Each block = (batch group g_b: 32 rows) x (hidden slice g_h: 16 units).
// Weights live in VGPRs as MFMA B-fragments (loaded once). Sibling h-exchange
// via fp16 ring + PER-WRITER release flags (no atomic RMW contention);
// layer l>0 polls producer-group flags before reading x from layer l-1's
// fp32 output. Input projection fused into the MFMA (A=[x_t | h_{t-1}], K=512).

typedef _Float16 half8   __attribute__((ext_vector_type(8)));
typedef _Float16 half4_t __attribute__((ext_vector_type(4)));
typedef float    floatx4 __attribute__((ext_vector_type(4)));

#define NB 32
#define GH 16
#define SZT ((size_t)(512 * 128 * 256))

// fp16 ring regions (4 slots x N x 256), offsets in halves
#define R1OFF (4 * 128 * 256)
#define R2OFF (R1OFF + 4 * 256 * 256)
#define RING_HALVES (R2OFF + 4 * 512 * 256)
#define NFLAGS 448

__device__ __forceinline__ float sigmf(float x) {
    return 1.0f / (1.0f + __expf(-x));
}
__device__ __forceinline__ float tanhfast(float x) {
    float e = __expf(-2.0f * fabsf(x));
    float r = (1.0f - e) / (1.0f + e);
    return copysignf(r, x);
}

__global__ __launch_bounds__(256) void fused_dlstm(
    const float* __restrict__ x0,
    const float* __restrict__ WihA,   // (3,1024,256)
    const float* __restrict__ WhhA,   // (3,1024,256)
    const float* __restrict__ bihA,   // (3,1024)
    const float* __restrict__ bhhA,   // (3,1024)
    float* __restrict__ outA,         // (3,512,128,256)
    _Float16* __restrict__ ringA,
    int* __restrict__ F)              // per-writer flags, 448 ints
{
    __shared__ _Float16 Abuf[NB][520];   // [row][0..255]=x, [256..511]=h, +8 pad
    __shared__ float scr[NB][68];

    const int tid  = threadIdx.x;
    const int lane = tid & 63;
    const int wv   = tid >> 6;
    const int bid  = blockIdx.x;

    int layer, G_b, rate, lbid, foff, roff;
    if (bid < 64)       { layer = 0; G_b = 4;  rate = 1; lbid = bid;       foff = 0;   roff = 0; }
    else if (bid < 192) { layer = 1; G_b = 8;  rate = 2; lbid = bid - 64;  foff = 64;  roff = R1OFF; }
    else                { layer = 2; G_b = 16; rate = 4; lbid = bid - 192; foff = 192; roff = R2OFF; }
    const int td   = 512 / rate;
    const int N    = 128 * rate;
    const int g_b  = lbid % G_b;
    const int g_h  = lbid / G_b;
    const int hid0 = g_h * 16;
    const int n0   = g_b * NB;

    const float* in    = (layer == 0) ? x0 : (outA + (size_t)(layer - 1) * SZT);
    float*       outL  = outA + (size_t)layer * SZT;
    _Float16*    ringL = ringA + roff;
    const size_t ringStride = (size_t)N * 256;

    int* sibF   = F + foff + g_b * GH;   // 16 contiguous flags of my group
    int* myFlag = sibF + g_h;
    const int tb = n0 >> 7;              // time sub-slot of this batch group
    int* prodF = nullptr;
    int  padd  = 0;                      // producer target = 2*t + padd
    if (layer == 1) { prodF = F + (((n0 & 127) >> 5) * GH);                          padd = tb + 1; }
    if (layer == 2) { prodF = F + 64 + ((((tb & 1) * 128 + (n0 & 127)) >> 5) * GH);  padd = (tb >> 1) + 1; }

    const float* Wih = WihA + (size_t)layer * 1024 * 256;
    const float* Whh = WhhA + (size_t)layer * 1024 * 256;
    const float* bih = bihA + (size_t)layer * 1024;
    const float* bhh = bhhA + (size_t)layer * 1024;

    // ---- weights -> register B fragments (once) ----
    half8 bfrag[16];
    {
        const int col  = lane & 15;
        const int q    = lane >> 4;
        const int grow = wv * 256 + hid0 + col;
        const float* wih_row = Wih + (size_t)grow * 256;
        const float* whh_row = Whh + (size_t)grow * 256;
#pragma unroll
        for (int ks = 0; ks < 16; ++ks) {
            const int k0 = ks * 32 + q * 8;
            const float* src = (k0 < 256) ? (wih_row + k0) : (whh_row + (k0 - 256));
            floatx4 w0 = *(const floatx4*)(src);
            floatx4 w1 = *(const floatx4*)(src + 4);
            half8 hb;
            hb[0] = (_Float16)w0[0]; hb[1] = (_Float16)w0[1];
            hb[2] = (_Float16)w0[2]; hb[3] = (_Float16)w0[3];
            hb[4] = (_Float16)w1[0]; hb[5] = (_Float16)w1[1];
            hb[6] = (_Float16)w1[2]; hb[7] = (_Float16)w1[3];
            bfrag[ks] = hb;
        }
    }

    const int erow = tid >> 4;
    const int ehid = tid & 15;
    const float bi = bih[0 * 256 + hid0 + ehid] + bhh[0 * 256 + hid0 + ehid];
    const float bf = bih[1 * 256 + hid0 + ehid] + bhh[1 * 256 + hid0 + ehid];
    const float bg = bih[2 * 256 + hid0 + ehid] + bhh[2 * 256 + hid0 + ehid];
    const float bo = bih[3 * 256 + hid0 + ehid] + bhh[3 * 256 + hid0 + ehid];
    float c0 = 0.0f, c1 = 0.0f;

    // layer-0 x prefetch (external input, dependency-free)
    floatx4 xp[8];
    if (layer == 0) {
#pragma unroll
        for (int i = 0; i < 8; ++i) {
            int id = tid + 256 * i, row = id >> 6, m = n0 + row;
            const float* p = in + ((size_t)(m >> 7) * 128 + (m & 127)) * 256
                             + (size_t)(id & 63) * 4;
            xp[i] = *(const floatx4*)p;
        }
    }

    for (int t = 0; t < td; ++t) {
        // ---- wait: sibling h(t-1) and/or producer x(t) ----
        const bool need_sib  = (t > 0);
        const bool need_prod = (layer > 0);
        if (need_sib | need_prod) {
            const int l16 = lane & 15;
            const int ptarget = 2 * t + padd;
            for (;;) {
                bool ok = true;
                if (need_sib)
                    ok &= (__hip_atomic_load(&sibF[l16], __ATOMIC_RELAXED,
                                             __HIP_MEMORY_SCOPE_AGENT) >= t);
                if (need_prod)
                    ok &= (__hip_atomic_load(&prodF[l16], __ATOMIC_RELAXED,
                                             __HIP_MEMORY_SCOPE_AGENT) >= ptarget);
                if (__all(ok)) break;
                __builtin_amdgcn_s_sleep(1);
            }
            if (need_sib)
                (void)__hip_atomic_load(&sibF[l16], __ATOMIC_ACQUIRE, __HIP_MEMORY_SCOPE_AGENT);
            if (need_prod)
                (void)__hip_atomic_load(&prodF[l16], __ATOMIC_ACQUIRE, __HIP_MEMORY_SCOPE_AGENT);
        }

        // ---- stage x(t) -> Abuf cols [0,256) ----
        if (layer == 0) {
#pragma unroll
            for (int i = 0; i < 8; ++i) {
                int id = tid + 256 * i, row = id >> 6, c4 = (id & 63) * 4;
                half4_t hx;
                hx[0] = (_Float16)xp[i][0]; hx[1] = (_Float16)xp[i][1];
                hx[2] = (_Float16)xp[i][2]; hx[3] = (_Float16)xp[i][3];
                *(half4_t*)&Abuf[row][c4] = hx;
            }
            if (t + 1 < td) {   // prefetch next x
#pragma unroll
                for (int i = 0; i < 8; ++i) {
                    int id = tid + 256 * i, row = id >> 6, m = n0 + row;
                    const float* p = in + ((size_t)((t + 1) * rate + (m >> 7)) * 128 + (m & 127)) * 256
                                     + (size_t)(id & 63) * 4;
                    xp[i] = *(const floatx4*)p;
                }
            }
        } else {
            // load from previous layer's fp32 output (guarded by producer flags)
#pragma unroll
            for (int i = 0; i < 8; ++i) {
                int id = tid + 256 * i, row = id >> 6, m = n0 + row;
                const float* p = in + ((size_t)(t * rate + (m >> 7)) * 128 + (m & 127)) * 256
                                 + (size_t)(id & 63) * 4;
                floatx4 v = *(const floatx4*)p;
                half4_t hx;
                hx[0] = (_Float16)v[0]; hx[1] = (_Float16)v[1];
                hx[2] = (_Float16)v[2]; hx[3] = (_Float16)v[3];
                *(half4_t*)&Abuf[row][(id & 63) * 4] = hx;
            }
        }

        // ---- stage h(t-1) -> Abuf cols [256,512) ----
        if (t > 0) {
            const _Float16* rs = ringL + (size_t)((t - 1) & 3) * ringStride;
#pragma unroll
            for (int i = 0; i < 4; ++i) {
                int id = tid + 256 * i, row = id >> 5, kc = id & 31, m = n0 + row;
                uint4 v = *(const uint4*)(rs + (size_t)m * 256 + kc * 8);
                *(uint4*)&Abuf[row][256 + kc * 8] = v;
            }
        } else {
#pragma unroll
            for (int i = 0; i < 4; ++i) {
                int id = tid + 256 * i, row = id >> 5, kc = id & 31;
                uint4 z = {0u, 0u, 0u, 0u};
                *(uint4*)&Abuf[row][256 + kc * 8] = z;
            }
        }
        __syncthreads();

        // ---- MFMA: wave wv = gate chunk, rows 0..15 and 16..31, K=512 ----
        floatx4 acc0 = {0.f, 0.f, 0.f, 0.f};
        floatx4 acc1 = {0.f, 0.f, 0.f, 0.f};
        {
            const int r = lane & 15, q = lane >> 4;
#pragma unroll
            for (int ks = 0; ks < 16; ++ks) {
                half8 a0 = *(const half8*)&Abuf[r][ks * 32 + q * 8];
                half8 a1 = *(const half8*)&Abuf[16 + r][ks * 32 + q * 8];
                acc0 = __builtin_amdgcn_mfma_f32_16x16x32_f16(a0, bfrag[ks], acc0, 0, 0, 0);
                acc1 = __builtin_amdgcn_mfma_f32_16x16x32_f16(a1, bfrag[ks], acc1, 0, 0, 0);
            }
        }
        {
            const int r = lane & 15, q = lane >> 4;
#pragma unroll
            for (int reg = 0; reg < 4; ++reg) {
                scr[q * 4 + reg][wv * 16 + r]      = acc0[reg];
                scr[16 + q * 4 + reg][wv * 16 + r] = acc1[reg];
            }
        }
        __syncthreads();

        // ---- elementwise LSTM cell + stores ----
        {
            float gi0 = scr[erow][ehid]           + bi;
            float gf0 = scr[erow][16 + ehid]      + bf;
            float gg0 = scr[erow][32 + ehid]      + bg;
            float go0 = scr[erow][48 + ehid]      + bo;
            float gi1 = scr[16 + erow][ehid]      + bi;
            float gf1 = scr[16 + erow][16 + ehid] + bf;
            float gg1 = scr[16 + erow][32 + ehid] + bg;
            float go1 = scr[16 + erow][48 + ehid] + bo;

            c0 = sigmf(gf0) * c0 + sigmf(gi0) * tanhfast(gg0);
            c1 = sigmf(gf1) * c1 + sigmf(gi1) * tanhfast(gg1);
            float h0v = sigmf(go0) * tanhfast(c0);
            float h1v = sigmf(go1) * tanhfast(c1);

            int m0 = n0 + erow, m1 = m0 + 16;
            int tau0 = t * rate + (m0 >> 7);
            int tau1 = t * rate + (m1 >> 7);
            outL[((size_t)tau0 * 128 + (m0 & 127)) * 256 + hid0 + ehid] = h0v;
            outL[((size_t)tau1 * 128 + (m1 & 127)) * 256 + hid0 + ehid] = h1v;

            _Float16* rw = ringL + (size_t)(t & 3) * ringStride;
            rw[(size_t)m0 * 256 + hid0 + ehid] = (_Float16)h0v;
            rw[(size_t)m1 * 256 + hid0 + ehid] = (_Float16)h1v;
        }

        // ---- release: barrier drains all waves' stores, then per-writer flag ----
        __syncthreads();
        if (tid == 0)
            __hip_atomic_store(myFlag, t + 1, __ATOMIC_RELEASE, __HIP_MEMORY_SCOPE_AGENT);
    }
}

extern "C" void kernel_launch(void* const* d_in, const int* in_sizes, int n_in,
                              void* d_out, int out_size, void* d_ws, size_t ws_size,
                              hipStream_t stream) {
    const float* x   = (const float*)d_in[0];
    const float* Wih = (const float*)d_in[1];
    const float* Whh = (const float*)d_in[2];
    const float* bih = (const float*)d_in[3];
    const float* bhh = (const float*)d_in[4];
    float* out = (float*)d_out;

    _Float16* ring = (_Float16*)d_ws;
    int* F = (int*)((char*)d_ws + (size_t)RING_HALVES * 2);
    hipMemsetAsync(F, 0, NFLAGS * sizeof(int), stream);

    fused_dlstm<<<dim3(448), dim3(256), 0, stream>>>(x, Wih, Whh, bih, bhh, out, ring, F);
}